// Round 2
// baseline (252.495 us; speedup 1.0000x reference)
//
#include <hip/hip_runtime.h>
#include <hip/hip_bf16.h>
#include <stdint.h>

// ---------------------------------------------------------------------------
// Attention_47330539602252 on MI355X (gfx950).
// I/O is fp32 (per reference dtypes); compute is bf16 MFMA + fp32 accumulate
// (harness compares with 2%-of-max bf16-tolerance threshold).
// B=8 N=1024 C=768 H=12 hd=64; quad2 norm: t=(s*0.125+5)^2, row-normalized.
// Pipeline: gemm_bt<0,1> (QKV, fp32 A/B -> bf16 q/k/v in ws)
//           -> attn_quad (bf16 in ws, fused; no online-max needed since
//              quad2 weights are polynomial, numerator/denominator linear)
//           -> gemm_bt<1,0> (proj: bf16 A, fp32 B, +bias, fp32 out).
// MFMA layouts (HW-verified, cdna_hip_programming.md §3):
//   A-frag: A[m=lane&15][k=quad*8+j]   B-frag: B[n=lane&15][k=quad*8+j]
//   C/D:    col=lane&15, row=quad*4+reg
// ---------------------------------------------------------------------------

typedef short  s8v  __attribute__((ext_vector_type(8)));  // 8 bf16 raw bits
typedef float  f4v  __attribute__((ext_vector_type(4)));

__device__ inline float bf2f(uint16_t h) {
    union { uint32_t u; float f; } c; c.u = ((uint32_t)h) << 16; return c.f;
}
__device__ inline uint16_t f2bf(float f) {
    union { float f; uint32_t u; } c; c.f = f;
    uint32_t u = c.u;
    u += 0x7fffu + ((u >> 16) & 1u);   // RNE
    return (uint16_t)(u >> 16);
}

// ---------------------------------------------------------------------------
// GEMM-BT: C[M,N] = A[M,K] @ Bm[N,K]^T, K%32==0. B is fp32 (weights).
// AF32: A is fp32 (x) else bf16 (ao in ws). Staging converts to bf16 LDS.
// Block tile 128x128, 4 waves (2x2), each wave 64x64 via 4x4 mfma tiles.
// EPI==0: scatter bf16 to q/k/v [B,H,N,64];  EPI==1: +bias, fp32 Cout[M,768].
// ---------------------------------------------------------------------------
template <int EPI, int AF32>
__global__ __launch_bounds__(256) void gemm_bt(
    const void* __restrict__ Ap, const float* __restrict__ Bm,
    uint16_t* __restrict__ qb, uint16_t* __restrict__ kb, uint16_t* __restrict__ vb,
    const float* __restrict__ bias, float* __restrict__ Cout, int K)
{
    const int tid  = threadIdx.x;
    const int wave = tid >> 6, lane = tid & 63;
    const int quad = lane >> 4, l16 = lane & 15;
    const int wM = wave >> 1, wN = wave & 1;
    const int bM = blockIdx.x, bN = blockIdx.y;

    __shared__ uint16_t Al[128][40];   // +8 pad; frag reads 2-way bank alias (free per m136)
    __shared__ uint16_t Bl[128][40];

    f4v acc[4][4];
#pragma unroll
    for (int i = 0; i < 4; i++)
#pragma unroll
        for (int j = 0; j < 4; j++) { f4v z = {0.f, 0.f, 0.f, 0.f}; acc[i][j] = z; }

    const float*    Af = (const float*)Ap    + (size_t)bM * 128 * K;
    const uint16_t* Ab = (const uint16_t*)Ap + (size_t)bM * 128 * K;
    const float*    Bf = Bm                  + (size_t)bN * 128 * K;

    for (int kc = 0; kc < K; kc += 32) {
        __syncthreads();
        if (AF32) {
            // A fp32: 128 rows x 32 k = 1024 float4 groups; 4 per thread
#pragma unroll
            for (int i = 0; i < 4; i++) {
                int idx = tid + i * 256;
                int row = idx >> 3, seg = idx & 7;       // seg: 4-float chunk
                float4 f = *reinterpret_cast<const float4*>(Af + (size_t)row * K + kc + seg * 4);
                ushort4 h; h.x = f2bf(f.x); h.y = f2bf(f.y); h.z = f2bf(f.z); h.w = f2bf(f.w);
                *reinterpret_cast<ushort4*>(&Al[row][seg * 4]) = h;
            }
        } else {
            // A bf16: 512 x 16B loads, 2 per thread
#pragma unroll
            for (int i = 0; i < 2; i++) {
                int idx = tid + i * 256;
                int row = idx >> 2, seg = idx & 3;       // seg: 8-bf16 chunk
                *reinterpret_cast<float4*>(&Al[row][seg * 8]) =
                    *reinterpret_cast<const float4*>(Ab + (size_t)row * K + kc + seg * 8);
            }
        }
        // B fp32 always
#pragma unroll
        for (int i = 0; i < 4; i++) {
            int idx = tid + i * 256;
            int row = idx >> 3, seg = idx & 7;
            float4 f = *reinterpret_cast<const float4*>(Bf + (size_t)row * K + kc + seg * 4);
            ushort4 h; h.x = f2bf(f.x); h.y = f2bf(f.y); h.z = f2bf(f.z); h.w = f2bf(f.w);
            *reinterpret_cast<ushort4*>(&Bl[row][seg * 4]) = h;
        }
        __syncthreads();

        s8v af[4], bf[4];
#pragma unroll
        for (int t = 0; t < 4; t++) {
            af[t] = *reinterpret_cast<const s8v*>(&Al[wM * 64 + t * 16 + l16][quad * 8]);
            bf[t] = *reinterpret_cast<const s8v*>(&Bl[wN * 64 + t * 16 + l16][quad * 8]);
        }
#pragma unroll
        for (int tm = 0; tm < 4; tm++)
#pragma unroll
            for (int tn = 0; tn < 4; tn++)
                acc[tm][tn] = __builtin_amdgcn_mfma_f32_16x16x32_bf16(af[tm], bf[tn], acc[tm][tn], 0, 0, 0);
    }

    // epilogue
#pragma unroll
    for (int tm = 0; tm < 4; tm++) {
#pragma unroll
        for (int tn = 0; tn < 4; tn++) {
            const int col = bN * 128 + wN * 64 + tn * 16 + l16;
#pragma unroll
            for (int reg = 0; reg < 4; reg++) {
                const int row = bM * 128 + wM * 64 + tm * 16 + quad * 4 + reg;
                float val = acc[tm][tn][reg];
                if (EPI == 0) {
                    // col in [0,2304): three = col/768, h = (col%768)/64, d = col%64
                    const int three = col / 768;
                    const int rem   = col - three * 768;
                    const int h = rem >> 6, d = rem & 63;
                    const int b = row >> 10, n = row & 1023;
                    uint16_t* dst = (three == 0) ? qb : ((three == 1) ? kb : vb);
                    dst[((size_t)((b * 12 + h) * 1024 + n)) * 64 + d] = f2bf(val);
                } else {
                    Cout[(size_t)row * 768 + col] = val + bias[col];
                }
            }
        }
    }
}

// ---------------------------------------------------------------------------
// Fused quad2 attention over bf16 q/k/v in ws. Grid: x=16 Q-tiles (64 rows),
// y=96 (b*12+h). 4 waves; wave w owns Q rows [qt*64+w*16, +16). m-loop over
// 16 x 64-col tiles: S=Q@K^T (mfma) -> t=(s/8+5)^2 -> rowsum (from bf16-
// rounded t, consistent with PV numerator) + P LDS round-trip (C-layout ->
// A-layout) -> U += P@V (V staged transposed). Final: O = U / rowsum.
// ---------------------------------------------------------------------------
__global__ __launch_bounds__(256) void attn_quad(
    const uint16_t* __restrict__ Q, const uint16_t* __restrict__ K,
    const uint16_t* __restrict__ V, uint16_t* __restrict__ O)
{
    const int qt = blockIdx.x;      // 0..15
    const int bh = blockIdx.y;      // 0..95 = b*12+h
    const size_t base = (size_t)bh * 1024 * 64;
    const uint16_t* Qp = Q + base;
    const uint16_t* Kp = K + base;
    const uint16_t* Vp = V + base;

    const int tid  = threadIdx.x;
    const int wave = tid >> 6, lane = tid & 63;
    const int quad = lane >> 4, l16 = lane & 15;

    __shared__ uint16_t Ql[64][72];      // [row][d]
    __shared__ uint16_t Kl[64][72];      // [m][d]
    __shared__ uint16_t Vl[64][72];      // transposed: [d][m]
    __shared__ uint16_t Pl[4][16][72];   // per-wave t tile [qrow][m]

    {
        const int row = tid & 63, dc = tid >> 6;
        const float4* s = reinterpret_cast<const float4*>(Qp + (size_t)(qt * 64 + row) * 64 + dc * 16);
        *reinterpret_cast<float4*>(&Ql[row][dc * 16])     = s[0];
        *reinterpret_cast<float4*>(&Ql[row][dc * 16 + 8]) = s[1];
    }
    __syncthreads();
    s8v qf0 = *reinterpret_cast<const s8v*>(&Ql[wave * 16 + l16][quad * 8]);
    s8v qf1 = *reinterpret_cast<const s8v*>(&Ql[wave * 16 + l16][32 + quad * 8]);

    f4v U[4];
#pragma unroll
    for (int i = 0; i < 4; i++) { f4v z = {0.f, 0.f, 0.f, 0.f}; U[i] = z; }
    float rowsum[4] = {0.f, 0.f, 0.f, 0.f};

    for (int mt = 0; mt < 16; mt++) {
        __syncthreads();   // previous iteration's Kl/Vl readers done
        {
            const int row = tid & 63, dc = tid >> 6;
            const float4* sk = reinterpret_cast<const float4*>(Kp + (size_t)(mt * 64 + row) * 64 + dc * 16);
            *reinterpret_cast<float4*>(&Kl[row][dc * 16])     = sk[0];
            *reinterpret_cast<float4*>(&Kl[row][dc * 16 + 8]) = sk[1];
            const float4* sv = reinterpret_cast<const float4*>(Vp + (size_t)(mt * 64 + row) * 64 + dc * 16);
            float4 a = sv[0], b = sv[1];
            const uint16_t* ea = reinterpret_cast<const uint16_t*>(&a);
            const uint16_t* eb = reinterpret_cast<const uint16_t*>(&b);
#pragma unroll
            for (int i = 0; i < 8; i++) Vl[dc * 16 + i][row]     = ea[i];
#pragma unroll
            for (int i = 0; i < 8; i++) Vl[dc * 16 + 8 + i][row] = eb[i];
        }
        __syncthreads();

        // S = Q @ K^T : wave's 16 rows x 64 cols = 4 C-tiles, K-dim 64
        f4v sacc[4];
#pragma unroll
        for (int ct = 0; ct < 4; ct++) {
            f4v z = {0.f, 0.f, 0.f, 0.f};
            s8v kf0 = *reinterpret_cast<const s8v*>(&Kl[ct * 16 + l16][quad * 8]);
            s8v kf1 = *reinterpret_cast<const s8v*>(&Kl[ct * 16 + l16][32 + quad * 8]);
            z = __builtin_amdgcn_mfma_f32_16x16x32_bf16(qf0, kf0, z, 0, 0, 0);
            z = __builtin_amdgcn_mfma_f32_16x16x32_bf16(qf1, kf1, z, 0, 0, 0);
            sacc[ct] = z;
        }

        // t = (s*0.125+5)^2 ; rowsum from bf16-rounded t ; P -> LDS (C->A layout)
        float part[4] = {0.f, 0.f, 0.f, 0.f};
#pragma unroll
        for (int ct = 0; ct < 4; ct++) {
#pragma unroll
            for (int reg = 0; reg < 4; reg++) {
                float s = sacc[ct][reg] * 0.125f + 5.0f;
                uint16_t tb = f2bf(s * s);
                part[reg] += bf2f(tb);
                Pl[wave][quad * 4 + reg][ct * 16 + l16] = tb;
            }
        }
#pragma unroll
        for (int off = 1; off < 16; off <<= 1) {
#pragma unroll
            for (int reg = 0; reg < 4; reg++) part[reg] += __shfl_xor(part[reg], off);
        }
#pragma unroll
        for (int reg = 0; reg < 4; reg++) rowsum[reg] += part[reg];

        // U += P @ V  (P wave-private in LDS; same-wave DS ops are in-order)
#pragma unroll
        for (int kc = 0; kc < 2; kc++) {
            s8v pf = *reinterpret_cast<const s8v*>(&Pl[wave][l16][kc * 32 + quad * 8]);
#pragma unroll
            for (int ct = 0; ct < 4; ct++) {
                s8v vf = *reinterpret_cast<const s8v*>(&Vl[ct * 16 + l16][kc * 32 + quad * 8]);
                U[ct] = __builtin_amdgcn_mfma_f32_16x16x32_bf16(pf, vf, U[ct], 0, 0, 0);
            }
        }
    }

    // epilogue: O[b, n, h*64+d] = U / rowsum  (bf16 intermediate in ws)
    const int b = bh / 12, h = bh - (bh / 12) * 12;
    float inv[4];
#pragma unroll
    for (int reg = 0; reg < 4; reg++) inv[reg] = 1.0f / rowsum[reg];
#pragma unroll
    for (int ct = 0; ct < 4; ct++) {
#pragma unroll
        for (int reg = 0; reg < 4; reg++) {
            const int n = qt * 64 + wave * 16 + quad * 4 + reg;
            const int d = ct * 16 + l16;
            O[((size_t)(b * 1024 + n)) * 768 + h * 64 + d] = f2bf(U[ct][reg] * inv[reg]);
        }
    }
}

// ---------------------------------------------------------------------------
extern "C" void kernel_launch(void* const* d_in, const int* in_sizes, int n_in,
                              void* d_out, int out_size, void* d_ws, size_t ws_size,
                              hipStream_t stream)
{
    const float* x      = (const float*)d_in[0];   // [8,1024,768] fp32
    const float* qkv_w  = (const float*)d_in[1];   // [2304,768]  fp32
    const float* proj_w = (const float*)d_in[2];   // [768,768]   fp32
    const float* proj_b = (const float*)d_in[3];   // [768]       fp32
    float* out = (float*)d_out;                    // [8,1024,768] fp32

    const size_t NEL = (size_t)8 * 1024 * 768;     // 6291456
    uint16_t* qb = (uint16_t*)d_ws;                // bf16 [B,H,N,64] each
    uint16_t* kb = qb + NEL;
    uint16_t* vb = kb + NEL;
    uint16_t* ao = vb + NEL;                       // bf16 attn out [8192,768]

    // QKV: [8192,768] @ [2304,768]^T -> scatter bf16 q/k/v
    gemm_bt<0, 1><<<dim3(64, 18), 256, 0, stream>>>(x, qkv_w, qb, kb, vb, nullptr, nullptr, 768);
    // fused quad2 attention -> ao [8192,768] bf16
    attn_quad<<<dim3(16, 96), 256, 0, stream>>>(qb, kb, vb, ao);
    // proj: [8192,768] @ [768,768]^T + bias -> fp32 out
    gemm_bt<1, 0><<<dim3(64, 6), 256, 0, stream>>>(ao, proj_w, nullptr, nullptr, nullptr, proj_b, out, 768);
}